// Round 7
// baseline (708.072 us; speedup 1.0000x reference)
//
#include <hip/hip_runtime.h>
#include <hip/hip_fp16.h>

#define NN 100000
#define NE 3200000
#define H  64

#define BSHIFT 7
#define BNODES 128
#define NB ((NN + BNODES - 1) / BNODES)          // 782

#define PTHREADS 1024
#define PCHUNK   8192
#define PEPT     (PCHUNK / PTHREADS)             // 8
#define NPBLK    ((NE + PCHUNK - 1) / PCHUNK)    // 391

#define ECAP 6144                                // per-bucket cap (mean 4096, sd ~64)
#define SCHUNK 98                                // ceil(NN/1024)

// ---------------- encoder + fused edge count (verified R3/R6) ----------------
__global__ __launch_bounds__(256) void encoder_count_kernel(
    const float* __restrict__ x,
    const float* __restrict__ W1, const float* __restrict__ b1,
    const float* __restrict__ W2, const float* __restrict__ b2,
    const int* __restrict__ src, int* __restrict__ counts,
    __half* __restrict__ h16)
{
    __shared__ float sh1[4][H];
    const int tid  = threadIdx.x;
    const int slot = tid >> 6;
    const int f    = tid & 63;
    const int node = blockIdx.x * 4 + slot;      // grid 25000 -> node < NN always

    const int e = blockIdx.x * 256 + tid;        // 6.4M threads cover NE
    if (e < NE) atomicAdd(&counts[src[e]], 1);

    {
        float acc = b1[f];
        #pragma unroll
        for (int k = 0; k < 6; ++k)
            acc = fmaf(x[node * 6 + k], W1[k * H + f], acc);
        sh1[slot][f] = fmaxf(acc, 0.0f);
    }
    __syncthreads();
    {
        float acc = b2[f];
        #pragma unroll 8
        for (int k = 0; k < H; ++k)
            acc = fmaf(sh1[slot][k], W2[k * H + f], acc);
        h16[node * H + f] = __float2half(acc);
    }
}

// ---------------- single-block scan: counts -> offs (exclusive) + bcursor -----------
__global__ __launch_bounds__(1024) void scan_kernel(
    const int* __restrict__ counts, int* __restrict__ offs, int* __restrict__ bcursor)
{
    __shared__ int s[1024];
    const int t  = threadIdx.x;
    const int lo = t * SCHUNK;
    const int hi = min(lo + SCHUNK, NN);
    int sum = 0;
    for (int i = lo; i < hi; ++i) sum += counts[i];
    s[t] = sum;
    __syncthreads();
    for (int off = 1; off < 1024; off <<= 1) {
        int xv = 0;
        if (t >= off) xv = s[t - off];
        __syncthreads();
        if (t >= off) s[t] += xv;
        __syncthreads();
    }
    int run = (t == 0) ? 0 : s[t - 1];           // exclusive prefix of chunk
    for (int i = lo; i < hi; ++i) {
        offs[i] = run;
        if ((i & (BNODES - 1)) == 0) bcursor[i >> BSHIFT] = run;
        run += counts[i];
    }
}

// ---------------- partition: edges -> bucket-grouped staging (verified R6) ----------
__global__ __launch_bounds__(PTHREADS) void partition_kernel(
    const int* __restrict__ src, const int* __restrict__ dst,
    int* __restrict__ bcursor, unsigned* __restrict__ staging)
{
    __shared__ unsigned stage[PCHUNK];   // 32 KB
    __shared__ int gpos[PCHUNK];         // 32 KB
    __shared__ int lh[NB];
    __shared__ int lcur[NB];
    __shared__ int gbase[NB];
    __shared__ int sscan[PTHREADS];
    const int t = threadIdx.x;
    const int cbase = blockIdx.x * PCHUNK;
    const int cnt = min(PCHUNK, NE - cbase);

    for (int i = t; i < NB; i += PTHREADS) lh[i] = 0;
    __syncthreads();

    unsigned ent[PEPT];
    int bkt[PEPT];
    #pragma unroll
    for (int j = 0; j < PEPT; ++j) {
        const int idx = t + j * PTHREADS;
        if (idx < cnt) {
            const int s_ = src[cbase + idx];
            const int d_ = dst[cbase + idx];
            bkt[j] = s_ >> BSHIFT;
            ent[j] = (unsigned)d_ | ((unsigned)(s_ & (BNODES - 1)) << 17);
            atomicAdd(&lh[bkt[j]], 1);
        } else bkt[j] = -1;
    }
    __syncthreads();

    const int hv = (t < NB) ? lh[t] : 0;
    sscan[t] = hv;
    __syncthreads();
    for (int off = 1; off < PTHREADS; off <<= 1) {
        int xv = 0;
        if (t >= off) xv = sscan[t - off];
        __syncthreads();
        if (t >= off) sscan[t] += xv;
        __syncthreads();
    }
    if (t < NB) {
        const int excl = sscan[t] - hv;
        lh[t]   = excl;
        lcur[t] = excl;
        gbase[t] = (hv > 0) ? atomicAdd(&bcursor[t], hv) : 0;
    }
    __syncthreads();

    #pragma unroll
    for (int j = 0; j < PEPT; ++j) {
        if (bkt[j] >= 0) {
            const int lp = atomicAdd(&lcur[bkt[j]], 1);
            stage[lp] = ent[j];
            gpos[lp]  = gbase[bkt[j]] + (lp - lh[bkt[j]]);
        }
    }
    __syncthreads();

    for (int i = t; i < cnt; i += PTHREADS)
        staging[gpos[i]] = stage[i];
}

// ---------------- bucket sort: staging -> node-ordered sdst (verified R6) -----------
__global__ __launch_bounds__(1024) void bucket_sort_kernel(
    const unsigned* __restrict__ staging, const int* __restrict__ offs,
    int* __restrict__ sdst)
{
    __shared__ int ldst[ECAP];           // 24 KB
    __shared__ int lcur[BNODES];
    const int t = threadIdx.x;
    const int b = blockIdx.x;
    const int nbase = b * BNODES;
    const int base0 = offs[nbase];
    const int endoff = (b == NB - 1) ? NE : offs[nbase + BNODES];
    const int ecnt = endoff - base0;
    const int nvalid = min(BNODES, NN - nbase);

    if (t < BNODES) lcur[t] = (t < nvalid) ? (offs[nbase + t] - base0) : 0;
    __syncthreads();
    for (int i = t; i < ecnt; i += 1024) {
        const unsigned ev = staging[base0 + i];
        const int lp = atomicAdd(&lcur[(int)(ev >> 17)], 1);
        ldst[lp] = (int)(ev & 0x1FFFFu);
    }
    __syncthreads();
    for (int i = t; i < ecnt; i += 1024)
        sdst[base0 + i] = ldst[i];
}

// ---------------- fused fp16 gather(mean) + MLP + heads (unroll 8) ----------------
__device__ __forceinline__ void addrow(float4& acc, uint2 v) {
    const float2 a = __half22float2(*(const __half2*)&v.x);
    const float2 c = __half22float2(*(const __half2*)&v.y);
    acc.x += a.x; acc.y += a.y; acc.z += c.x; acc.w += c.y;
}

__global__ __launch_bounds__(256) void gather_head_kernel(
    const __half* __restrict__ h16,
    const int* __restrict__ counts, const int* __restrict__ offs,
    const int* __restrict__ sdst,
    const float* __restrict__ Wf1, const float* __restrict__ bf1,
    const float* __restrict__ Wf2, const float* __restrict__ bf2,
    const float* __restrict__ Ws1, const float* __restrict__ bs1,
    const float* __restrict__ Ws2, const float* __restrict__ bs2,
    const float* __restrict__ Wt1, const float* __restrict__ bt1,
    const float* __restrict__ Wt2, const float* __restrict__ bt2,
    float* __restrict__ out_scores, float* __restrict__ out_types)
{
    __shared__ __align__(16) float sa[4][H];
    __shared__ float sb[4][H];
    const int tid  = threadIdx.x;
    const int slot = tid >> 6;
    const int f    = tid & 63;
    const int node = blockIdx.x * 4 + slot;   // grid 25000 -> node < NN always

    const int deg   = counts[node];
    const int start = offs[node];

    const int grp = f >> 4;
    const int q   = f & 15;
    const uint2* __restrict__ hp = (const uint2*)h16;

    const uint2 sv = hp[node * 16 + q];       // self row, issued early

    const int qlen   = (deg + 3) >> 2;
    const int gstart = start + grp * qlen;
    int gcnt = deg - grp * qlen;
    gcnt = (gcnt < 0) ? 0 : ((gcnt > qlen) ? qlen : gcnt);

    float4 acc = make_float4(0.f, 0.f, 0.f, 0.f);
    int j = 0;
    const int jmax = gcnt & ~7;
    for (; j < jmax; j += 8) {                // 8 rows in flight
        const int d0 = sdst[gstart + j + 0];
        const int d1 = sdst[gstart + j + 1];
        const int d2 = sdst[gstart + j + 2];
        const int d3 = sdst[gstart + j + 3];
        const int d4 = sdst[gstart + j + 4];
        const int d5 = sdst[gstart + j + 5];
        const int d6 = sdst[gstart + j + 6];
        const int d7 = sdst[gstart + j + 7];
        const uint2 v0 = hp[d0 * 16 + q];
        const uint2 v1 = hp[d1 * 16 + q];
        const uint2 v2 = hp[d2 * 16 + q];
        const uint2 v3 = hp[d3 * 16 + q];
        const uint2 v4 = hp[d4 * 16 + q];
        const uint2 v5 = hp[d5 * 16 + q];
        const uint2 v6 = hp[d6 * 16 + q];
        const uint2 v7 = hp[d7 * 16 + q];
        addrow(acc, v0); addrow(acc, v1); addrow(acc, v2); addrow(acc, v3);
        addrow(acc, v4); addrow(acc, v5); addrow(acc, v6); addrow(acc, v7);
    }
    if (j + 4 <= gcnt) {
        const int d0 = sdst[gstart + j + 0];
        const int d1 = sdst[gstart + j + 1];
        const int d2 = sdst[gstart + j + 2];
        const int d3 = sdst[gstart + j + 3];
        const uint2 v0 = hp[d0 * 16 + q];
        const uint2 v1 = hp[d1 * 16 + q];
        const uint2 v2 = hp[d2 * 16 + q];
        const uint2 v3 = hp[d3 * 16 + q];
        addrow(acc, v0); addrow(acc, v1); addrow(acc, v2); addrow(acc, v3);
        j += 4;
    }
    for (; j < gcnt; ++j) {
        const int d = sdst[gstart + j];
        const uint2 v = hp[d * 16 + q];
        addrow(acc, v);
    }

    #pragma unroll
    for (int off = 16; off < 64; off <<= 1) {
        acc.x += __shfl_xor(acc.x, off);
        acc.y += __shfl_xor(acc.y, off);
        acc.z += __shfl_xor(acc.z, off);
        acc.w += __shfl_xor(acc.w, off);
    }

    if (grp == 0) {
        const float inv = 1.0f / fmaxf((float)deg, 1.0f);
        float4 self = make_float4(0.f, 0.f, 0.f, 0.f);
        addrow(self, sv);
        float4 r;
        r.x = self.x + acc.x * inv;
        r.y = self.y + acc.y * inv;
        r.z = self.z + acc.z * inv;
        r.w = self.w + acc.w * inv;
        ((float4*)sa[slot])[q] = r;
    }
    __syncthreads();

    {
        float a2 = bf1[f];
        #pragma unroll 8
        for (int k = 0; k < H; ++k)
            a2 = fmaf(sa[slot][k], Wf1[k * H + f], a2);
        sb[slot][f] = fmaxf(a2, 0.0f);
    }
    __syncthreads();

    {
        float a2 = bf2[f];
        #pragma unroll 8
        for (int k = 0; k < H; ++k)
            a2 = fmaf(sb[slot][k], Wf2[k * H + f], a2);
        sa[slot][f] = fmaxf(a2, 0.0f);
    }
    __syncthreads();

    {
        if (f < 32) {
            float a2 = bs1[f];
            #pragma unroll 8
            for (int k = 0; k < H; ++k)
                a2 = fmaf(sa[slot][k], Ws1[k * 32 + f], a2);
            sb[slot][f] = fmaxf(a2, 0.0f);
        } else {
            const int jj = f - 32;
            float a2 = bt1[jj];
            #pragma unroll 8
            for (int k = 0; k < H; ++k)
                a2 = fmaf(sa[slot][k], Wt1[k * 32 + jj], a2);
            sb[slot][32 + jj] = fmaxf(a2, 0.0f);
        }
    }
    __syncthreads();

    {
        if (f == 0) {
            float a2 = bs2[0];
            #pragma unroll 8
            for (int jj = 0; jj < 32; ++jj)
                a2 = fmaf(sb[slot][jj], Ws2[jj], a2);
            out_scores[node] = a2;
        } else if (f >= 1 && f < 5) {
            const int c = f - 1;
            float a2 = bt2[c];
            #pragma unroll 8
            for (int jj = 0; jj < 32; ++jj)
                a2 = fmaf(sb[slot][32 + jj], Wt2[jj * 4 + c], a2);
            out_types[node * 4 + c] = a2;
        }
    }
}

extern "C" void kernel_launch(void* const* d_in, const int* in_sizes, int n_in,
                              void* d_out, int out_size, void* d_ws, size_t ws_size,
                              hipStream_t stream)
{
    const float* x   = (const float*)d_in[0];
    const int*   adj = (const int*)  d_in[1];   // [2, E]: src = adj[0:E], dst = adj[E:2E]
    const float* W1  = (const float*)d_in[2];
    const float* b1  = (const float*)d_in[3];
    const float* W2  = (const float*)d_in[4];
    const float* b2  = (const float*)d_in[5];
    const float* Wf1 = (const float*)d_in[6];
    const float* bf1 = (const float*)d_in[7];
    const float* Wf2 = (const float*)d_in[8];
    const float* bf2 = (const float*)d_in[9];
    const float* Ws1 = (const float*)d_in[10];
    const float* bs1 = (const float*)d_in[11];
    const float* Ws2 = (const float*)d_in[12];
    const float* bs2 = (const float*)d_in[13];
    const float* Wt1 = (const float*)d_in[14];
    const float* bt1 = (const float*)d_in[15];
    const float* Wt2 = (const float*)d_in[16];
    const float* bt2 = (const float*)d_in[17];

    float* out_scores = (float*)d_out;          // [N]
    float* out_types  = out_scores + NN;        // [N,4]

    // ws: staging [NE u32] | h16 [NN*H half] | counts [NN] | offs [NN]
    //     | bcursor [NB] | sdst [NE]
    unsigned* staging  = (unsigned*)d_ws;
    __half*   h16      = (__half*)(staging + NE);
    int*      counts   = (int*)(h16 + (size_t)NN * H);
    int*      offs     = counts + NN;
    int*      bcursor  = offs + NN;
    int*      sdst     = bcursor + NB;

    const int* src = adj;
    const int* dst = adj + NE;

    hipMemsetAsync(counts, 0, NN * sizeof(int), stream);

    encoder_count_kernel<<<NN / 4, 256, 0, stream>>>(x, W1, b1, W2, b2, src, counts, h16);
    scan_kernel<<<1, 1024, 0, stream>>>(counts, offs, bcursor);
    partition_kernel<<<NPBLK, PTHREADS, 0, stream>>>(src, dst, bcursor, staging);
    bucket_sort_kernel<<<NB, 1024, 0, stream>>>(staging, offs, sdst);
    gather_head_kernel<<<NN / 4, 256, 0, stream>>>(h16, counts, offs, sdst,
                                                   Wf1, bf1, Wf2, bf2,
                                                   Ws1, bs1, Ws2, bs2,
                                                   Wt1, bt1, Wt2, bt2,
                                                   out_scores, out_types);
}

// Round 8
// 546.343 us; speedup vs baseline: 1.2960x; 1.2960x over previous
//
#include <hip/hip_runtime.h>
#include <hip/hip_fp16.h>

#define NN 100000
#define NE 3200000
#define H  64

#define SCAN_BLOCK 256
#define SCAN_ITEMS 4
#define SCAN_TILE  1024
#define NB1 ((NN + SCAN_TILE - 1) / SCAN_TILE)   // 98

#define BSHIFT 7
#define BNODES 128
#define NB ((NN + BNODES - 1) / BNODES)          // 782

#define PTHREADS 1024
#define PCHUNK   8192
#define PEPT     (PCHUNK / PTHREADS)             // 8
#define NPBLK    ((NE + PCHUNK - 1) / PCHUNK)    // 391

#define ECAP 6144                                // per-bucket cap (mean 4096, sd ~64)

// ---------------- encoder + fused edge count (verified R6) ----------------
__global__ __launch_bounds__(256) void encoder_count_kernel(
    const float* __restrict__ x,
    const float* __restrict__ W1, const float* __restrict__ b1,
    const float* __restrict__ W2, const float* __restrict__ b2,
    const int* __restrict__ src, int* __restrict__ counts,
    __half* __restrict__ h16)
{
    __shared__ float sh1[4][H];
    const int tid  = threadIdx.x;
    const int slot = tid >> 6;
    const int f    = tid & 63;
    const int node = blockIdx.x * 4 + slot;      // grid 25000 -> node < NN always

    const int e = blockIdx.x * 256 + tid;        // 6.4M threads cover NE
    if (e < NE) atomicAdd(&counts[src[e]], 1);

    {
        float acc = b1[f];
        #pragma unroll
        for (int k = 0; k < 6; ++k)
            acc = fmaf(x[node * 6 + k], W1[k * H + f], acc);
        sh1[slot][f] = fmaxf(acc, 0.0f);
    }
    __syncthreads();
    {
        float acc = b2[f];
        #pragma unroll 8
        for (int k = 0; k < H; ++k)
            acc = fmaf(sh1[slot][k], W2[k * H + f], acc);
        h16[node * H + f] = __float2half(acc);
    }
}

// ---------------- node-level exclusive scan (verified R6, 3 kernels) ----------------
__global__ __launch_bounds__(256) void scan1_kernel(
    const int* __restrict__ counts, int* __restrict__ offs, int* __restrict__ partials)
{
    __shared__ int s[SCAN_BLOCK];
    const int t = threadIdx.x, bid = blockIdx.x;
    const int base = bid * SCAN_TILE + t * SCAN_ITEMS;
    int v[SCAN_ITEMS];
    int sum = 0;
    #pragma unroll
    for (int j = 0; j < SCAN_ITEMS; ++j) {
        const int i = base + j;
        v[j] = (i < NN) ? counts[i] : 0;
        sum += v[j];
    }
    s[t] = sum;
    __syncthreads();
    for (int off = 1; off < SCAN_BLOCK; off <<= 1) {
        int xv = 0;
        if (t >= off) xv = s[t - off];
        __syncthreads();
        if (t >= off) s[t] += xv;
        __syncthreads();
    }
    int excl = s[t] - sum;
    #pragma unroll
    for (int j = 0; j < SCAN_ITEMS; ++j) {
        const int i = base + j;
        if (i < NN) offs[i] = excl;
        excl += v[j];
    }
    if (t == SCAN_BLOCK - 1) partials[bid] = s[t];
}

__global__ __launch_bounds__(128) void scan2_kernel(int* __restrict__ partials)
{
    __shared__ int s[128];
    const int t = threadIdx.x;
    const int v = (t < NB1) ? partials[t] : 0;
    s[t] = v;
    __syncthreads();
    for (int off = 1; off < 128; off <<= 1) {
        int xv = 0;
        if (t >= off) xv = s[t - off];
        __syncthreads();
        if (t >= off) s[t] += xv;
        __syncthreads();
    }
    if (t < NB1) partials[t] = s[t] - v;
}

__global__ __launch_bounds__(256) void scan3_kernel(
    int* __restrict__ offs, const int* __restrict__ partials, int* __restrict__ bcursor)
{
    const int t = threadIdx.x, bid = blockIdx.x;
    const int add = partials[bid];
    const int base = bid * SCAN_TILE + t * SCAN_ITEMS;
    #pragma unroll
    for (int j = 0; j < SCAN_ITEMS; ++j) {
        const int i = base + j;
        if (i < NN) {
            const int o = offs[i] + add;
            offs[i] = o;
            if ((i & (BNODES - 1)) == 0) bcursor[i >> BSHIFT] = o;
        }
    }
}

// ---------------- partition: edges -> bucket-grouped staging (verified R6) ----------
__global__ __launch_bounds__(PTHREADS) void partition_kernel(
    const int* __restrict__ src, const int* __restrict__ dst,
    int* __restrict__ bcursor, unsigned* __restrict__ staging)
{
    __shared__ unsigned stage[PCHUNK];   // 32 KB
    __shared__ int gpos[PCHUNK];         // 32 KB
    __shared__ int lh[NB];
    __shared__ int lcur[NB];
    __shared__ int gbase[NB];
    __shared__ int sscan[PTHREADS];
    const int t = threadIdx.x;
    const int cbase = blockIdx.x * PCHUNK;
    const int cnt = min(PCHUNK, NE - cbase);

    for (int i = t; i < NB; i += PTHREADS) lh[i] = 0;
    __syncthreads();

    unsigned ent[PEPT];
    int bkt[PEPT];
    #pragma unroll
    for (int j = 0; j < PEPT; ++j) {
        const int idx = t + j * PTHREADS;
        if (idx < cnt) {
            const int s_ = src[cbase + idx];
            const int d_ = dst[cbase + idx];
            bkt[j] = s_ >> BSHIFT;
            ent[j] = (unsigned)d_ | ((unsigned)(s_ & (BNODES - 1)) << 17);
            atomicAdd(&lh[bkt[j]], 1);
        } else bkt[j] = -1;
    }
    __syncthreads();

    const int hv = (t < NB) ? lh[t] : 0;
    sscan[t] = hv;
    __syncthreads();
    for (int off = 1; off < PTHREADS; off <<= 1) {
        int xv = 0;
        if (t >= off) xv = sscan[t - off];
        __syncthreads();
        if (t >= off) sscan[t] += xv;
        __syncthreads();
    }
    if (t < NB) {
        const int excl = sscan[t] - hv;
        lh[t]   = excl;
        lcur[t] = excl;
        gbase[t] = (hv > 0) ? atomicAdd(&bcursor[t], hv) : 0;
    }
    __syncthreads();

    #pragma unroll
    for (int j = 0; j < PEPT; ++j) {
        if (bkt[j] >= 0) {
            const int lp = atomicAdd(&lcur[bkt[j]], 1);
            stage[lp] = ent[j];
            gpos[lp]  = gbase[bkt[j]] + (lp - lh[bkt[j]]);
        }
    }
    __syncthreads();

    for (int i = t; i < cnt; i += PTHREADS)
        staging[gpos[i]] = stage[i];
}

// ---------------- bucket sort: staging -> node-ordered sdst (verified R6) -----------
__global__ __launch_bounds__(1024) void bucket_sort_kernel(
    const unsigned* __restrict__ staging, const int* __restrict__ offs,
    int* __restrict__ sdst)
{
    __shared__ int ldst[ECAP];           // 24 KB
    __shared__ int lcur[BNODES];
    const int t = threadIdx.x;
    const int b = blockIdx.x;
    const int nbase = b * BNODES;
    const int base0 = offs[nbase];
    const int endoff = (b == NB - 1) ? NE : offs[nbase + BNODES];
    const int ecnt = endoff - base0;
    const int nvalid = min(BNODES, NN - nbase);

    if (t < BNODES) lcur[t] = (t < nvalid) ? (offs[nbase + t] - base0) : 0;
    __syncthreads();
    for (int i = t; i < ecnt; i += 1024) {
        const unsigned ev = staging[base0 + i];
        const int lp = atomicAdd(&lcur[(int)(ev >> 17)], 1);
        ldst[lp] = (int)(ev & 0x1FFFFu);
    }
    __syncthreads();
    for (int i = t; i < ecnt; i += 1024)
        sdst[base0 + i] = ldst[i];
}

// ------ fused gather(mean) + MLP + heads: wave-UNIFORM fp16 row reads ------
__global__ __launch_bounds__(256) void gather_head_kernel(
    const __half* __restrict__ h16,
    const int* __restrict__ counts, const int* __restrict__ offs,
    const int* __restrict__ sdst,
    const float* __restrict__ Wf1, const float* __restrict__ bf1,
    const float* __restrict__ Wf2, const float* __restrict__ bf2,
    const float* __restrict__ Ws1, const float* __restrict__ bs1,
    const float* __restrict__ Ws2, const float* __restrict__ bs2,
    const float* __restrict__ Wt1, const float* __restrict__ bt1,
    const float* __restrict__ Wt2, const float* __restrict__ bt2,
    float* __restrict__ out_scores, float* __restrict__ out_types)
{
    __shared__ float sa[4][H];
    __shared__ float sb[4][H];
    const int tid  = threadIdx.x;
    const int slot = tid >> 6;
    const int f    = tid & 63;
    const int node = blockIdx.x * 4 + slot;   // grid 25000 -> node < NN always

    const int deg   = counts[node];
    const int start = offs[node];

    const float selfv = __half2float(h16[(size_t)node * H + f]);  // issued early

    // per-edge: ONE wave-uniform 128 B row read (2 B/lane), index via shfl broadcast
    float acc = 0.0f;
    for (int base = 0; base < deg; base += 64) {
        const int m = min(64, deg - base);
        int idx = 0;
        if (base + f < deg) idx = sdst[start + base + f];   // coalesced vector load

        int jj = 0;
        for (; jj + 8 <= m; jj += 8) {                      // 8 uniform rows in flight
            const int d0 = __shfl(idx, jj + 0);
            const int d1 = __shfl(idx, jj + 1);
            const int d2 = __shfl(idx, jj + 2);
            const int d3 = __shfl(idx, jj + 3);
            const int d4 = __shfl(idx, jj + 4);
            const int d5 = __shfl(idx, jj + 5);
            const int d6 = __shfl(idx, jj + 6);
            const int d7 = __shfl(idx, jj + 7);
            const __half v0 = h16[(size_t)d0 * H + f];
            const __half v1 = h16[(size_t)d1 * H + f];
            const __half v2 = h16[(size_t)d2 * H + f];
            const __half v3 = h16[(size_t)d3 * H + f];
            const __half v4 = h16[(size_t)d4 * H + f];
            const __half v5 = h16[(size_t)d5 * H + f];
            const __half v6 = h16[(size_t)d6 * H + f];
            const __half v7 = h16[(size_t)d7 * H + f];
            acc += __half2float(v0) + __half2float(v1)
                 + __half2float(v2) + __half2float(v3)
                 + __half2float(v4) + __half2float(v5)
                 + __half2float(v6) + __half2float(v7);
        }
        for (; jj < m; ++jj) {
            const int d = __shfl(idx, jj);
            acc += __half2float(h16[(size_t)d * H + f]);
        }
    }

    const float inv = 1.0f / fmaxf((float)deg, 1.0f);
    sa[slot][f] = selfv + acc * inv;
    __syncthreads();

    {
        float a2 = bf1[f];
        #pragma unroll 8
        for (int k = 0; k < H; ++k)
            a2 = fmaf(sa[slot][k], Wf1[k * H + f], a2);
        sb[slot][f] = fmaxf(a2, 0.0f);
    }
    __syncthreads();

    {
        float a2 = bf2[f];
        #pragma unroll 8
        for (int k = 0; k < H; ++k)
            a2 = fmaf(sb[slot][k], Wf2[k * H + f], a2);
        sa[slot][f] = fmaxf(a2, 0.0f);
    }
    __syncthreads();

    {
        if (f < 32) {
            float a2 = bs1[f];
            #pragma unroll 8
            for (int k = 0; k < H; ++k)
                a2 = fmaf(sa[slot][k], Ws1[k * 32 + f], a2);
            sb[slot][f] = fmaxf(a2, 0.0f);
        } else {
            const int jj = f - 32;
            float a2 = bt1[jj];
            #pragma unroll 8
            for (int k = 0; k < H; ++k)
                a2 = fmaf(sa[slot][k], Wt1[k * 32 + jj], a2);
            sb[slot][32 + jj] = fmaxf(a2, 0.0f);
        }
    }
    __syncthreads();

    {
        if (f == 0) {
            float a2 = bs2[0];
            #pragma unroll 8
            for (int jj = 0; jj < 32; ++jj)
                a2 = fmaf(sb[slot][jj], Ws2[jj], a2);
            out_scores[node] = a2;
        } else if (f >= 1 && f < 5) {
            const int c = f - 1;
            float a2 = bt2[c];
            #pragma unroll 8
            for (int jj = 0; jj < 32; ++jj)
                a2 = fmaf(sb[slot][32 + jj], Wt2[jj * 4 + c], a2);
            out_types[node * 4 + c] = a2;
        }
    }
}

extern "C" void kernel_launch(void* const* d_in, const int* in_sizes, int n_in,
                              void* d_out, int out_size, void* d_ws, size_t ws_size,
                              hipStream_t stream)
{
    const float* x   = (const float*)d_in[0];
    const int*   adj = (const int*)  d_in[1];   // [2, E]: src = adj[0:E], dst = adj[E:2E]
    const float* W1  = (const float*)d_in[2];
    const float* b1  = (const float*)d_in[3];
    const float* W2  = (const float*)d_in[4];
    const float* b2  = (const float*)d_in[5];
    const float* Wf1 = (const float*)d_in[6];
    const float* bf1 = (const float*)d_in[7];
    const float* Wf2 = (const float*)d_in[8];
    const float* bf2 = (const float*)d_in[9];
    const float* Ws1 = (const float*)d_in[10];
    const float* bs1 = (const float*)d_in[11];
    const float* Ws2 = (const float*)d_in[12];
    const float* bs2 = (const float*)d_in[13];
    const float* Wt1 = (const float*)d_in[14];
    const float* bt1 = (const float*)d_in[15];
    const float* Wt2 = (const float*)d_in[16];
    const float* bt2 = (const float*)d_in[17];

    float* out_scores = (float*)d_out;          // [N]
    float* out_types  = out_scores + NN;        // [N,4]

    // ws: staging [NE u32] | h16 [NN*H half] | counts [NN] | offs [NN] | partials [128]
    //     | bcursor [NB] | sdst [NE]
    unsigned* staging  = (unsigned*)d_ws;
    __half*   h16      = (__half*)(staging + NE);
    int*      counts   = (int*)(h16 + (size_t)NN * H);
    int*      offs     = counts + NN;
    int*      partials = offs + NN;
    int*      bcursor  = partials + 128;
    int*      sdst     = bcursor + NB;

    const int* src = adj;
    const int* dst = adj + NE;

    hipMemsetAsync(counts, 0, NN * sizeof(int), stream);

    encoder_count_kernel<<<NN / 4, 256, 0, stream>>>(x, W1, b1, W2, b2, src, counts, h16);
    scan1_kernel<<<NB1, SCAN_BLOCK, 0, stream>>>(counts, offs, partials);
    scan2_kernel<<<1, 128, 0, stream>>>(partials);
    scan3_kernel<<<NB1, SCAN_BLOCK, 0, stream>>>(offs, partials, bcursor);
    partition_kernel<<<NPBLK, PTHREADS, 0, stream>>>(src, dst, bcursor, staging);
    bucket_sort_kernel<<<NB, 1024, 0, stream>>>(staging, offs, sdst);
    gather_head_kernel<<<NN / 4, 256, 0, stream>>>(h16, counts, offs, sdst,
                                                   Wf1, bf1, Wf2, bf2,
                                                   Ws1, bs1, Ws2, bs2,
                                                   Wt1, bt1, Wt2, bt2,
                                                   out_scores, out_types);
}

// Round 9
// 543.765 us; speedup vs baseline: 1.3022x; 1.0047x over previous
//
#include <hip/hip_runtime.h>
#include <hip/hip_fp16.h>

#define NN 100000
#define NE 3200000
#define H  64

#define SCAN_BLOCK 256
#define SCAN_ITEMS 4
#define SCAN_TILE  1024
#define NB1 ((NN + SCAN_TILE - 1) / SCAN_TILE)   // 98

#define BSHIFT 7
#define BNODES 128
#define NB ((NN + BNODES - 1) / BNODES)          // 782

#define PTHREADS 1024
#define PCHUNK   8192
#define PEPT     (PCHUNK / PTHREADS)             // 8
#define NPBLK    ((NE + PCHUNK - 1) / PCHUNK)    // 391

#define ECAP 6144                                // per-bucket cap (mean 4096, sd ~64)

// ---------------- encoder + fused edge count (verified R6) ----------------
__global__ __launch_bounds__(256) void encoder_count_kernel(
    const float* __restrict__ x,
    const float* __restrict__ W1, const float* __restrict__ b1,
    const float* __restrict__ W2, const float* __restrict__ b2,
    const int* __restrict__ src, int* __restrict__ counts,
    __half* __restrict__ h16)
{
    __shared__ float sh1[4][H];
    const int tid  = threadIdx.x;
    const int slot = tid >> 6;
    const int f    = tid & 63;
    const int node = blockIdx.x * 4 + slot;      // grid 25000 -> node < NN always

    const int e = blockIdx.x * 256 + tid;        // 6.4M threads cover NE
    if (e < NE) atomicAdd(&counts[src[e]], 1);

    {
        float acc = b1[f];
        #pragma unroll
        for (int k = 0; k < 6; ++k)
            acc = fmaf(x[node * 6 + k], W1[k * H + f], acc);
        sh1[slot][f] = fmaxf(acc, 0.0f);
    }
    __syncthreads();
    {
        float acc = b2[f];
        #pragma unroll 8
        for (int k = 0; k < H; ++k)
            acc = fmaf(sh1[slot][k], W2[k * H + f], acc);
        h16[node * H + f] = __float2half(acc);
    }
}

// ---------------- node-level exclusive scan (verified R6, 3 kernels) ----------------
__global__ __launch_bounds__(256) void scan1_kernel(
    const int* __restrict__ counts, int* __restrict__ offs, int* __restrict__ partials)
{
    __shared__ int s[SCAN_BLOCK];
    const int t = threadIdx.x, bid = blockIdx.x;
    const int base = bid * SCAN_TILE + t * SCAN_ITEMS;
    int v[SCAN_ITEMS];
    int sum = 0;
    #pragma unroll
    for (int j = 0; j < SCAN_ITEMS; ++j) {
        const int i = base + j;
        v[j] = (i < NN) ? counts[i] : 0;
        sum += v[j];
    }
    s[t] = sum;
    __syncthreads();
    for (int off = 1; off < SCAN_BLOCK; off <<= 1) {
        int xv = 0;
        if (t >= off) xv = s[t - off];
        __syncthreads();
        if (t >= off) s[t] += xv;
        __syncthreads();
    }
    int excl = s[t] - sum;
    #pragma unroll
    for (int j = 0; j < SCAN_ITEMS; ++j) {
        const int i = base + j;
        if (i < NN) offs[i] = excl;
        excl += v[j];
    }
    if (t == SCAN_BLOCK - 1) partials[bid] = s[t];
}

__global__ __launch_bounds__(128) void scan2_kernel(int* __restrict__ partials)
{
    __shared__ int s[128];
    const int t = threadIdx.x;
    const int v = (t < NB1) ? partials[t] : 0;
    s[t] = v;
    __syncthreads();
    for (int off = 1; off < 128; off <<= 1) {
        int xv = 0;
        if (t >= off) xv = s[t - off];
        __syncthreads();
        if (t >= off) s[t] += xv;
        __syncthreads();
    }
    if (t < NB1) partials[t] = s[t] - v;
}

__global__ __launch_bounds__(256) void scan3_kernel(
    int* __restrict__ offs, const int* __restrict__ partials, int* __restrict__ bcursor)
{
    const int t = threadIdx.x, bid = blockIdx.x;
    const int add = partials[bid];
    const int base = bid * SCAN_TILE + t * SCAN_ITEMS;
    #pragma unroll
    for (int j = 0; j < SCAN_ITEMS; ++j) {
        const int i = base + j;
        if (i < NN) {
            const int o = offs[i] + add;
            offs[i] = o;
            if ((i & (BNODES - 1)) == 0) bcursor[i >> BSHIFT] = o;
        }
    }
}

// ---------------- partition: edges -> bucket-grouped staging ----------------
// (verified R6 structure; block scan replaced by wave-shfl scan: 20 barriers -> 2)
__global__ __launch_bounds__(PTHREADS) void partition_kernel(
    const int* __restrict__ src, const int* __restrict__ dst,
    int* __restrict__ bcursor, unsigned* __restrict__ staging)
{
    __shared__ unsigned stage[PCHUNK];   // 32 KB
    __shared__ int gpos[PCHUNK];         // 32 KB
    __shared__ int lh[NB];
    __shared__ int lcur[NB];
    __shared__ int gbase[NB];
    __shared__ int wtot[16];
    const int t = threadIdx.x;
    const int lane = t & 63;
    const int wid  = t >> 6;
    const int cbase = blockIdx.x * PCHUNK;
    const int cnt = min(PCHUNK, NE - cbase);

    for (int i = t; i < NB; i += PTHREADS) lh[i] = 0;
    __syncthreads();

    unsigned ent[PEPT];
    int bkt[PEPT];
    #pragma unroll
    for (int j = 0; j < PEPT; ++j) {
        const int idx = t + j * PTHREADS;
        if (idx < cnt) {
            const int s_ = src[cbase + idx];
            const int d_ = dst[cbase + idx];
            bkt[j] = s_ >> BSHIFT;
            ent[j] = (unsigned)d_ | ((unsigned)(s_ & (BNODES - 1)) << 17);
            atomicAdd(&lh[bkt[j]], 1);
        } else bkt[j] = -1;
    }
    __syncthreads();

    // wave-shfl exclusive scan over lh[0..NB) laid on threads 0..1023
    const int hv = (t < NB) ? lh[t] : 0;
    int incl = hv;
    #pragma unroll
    for (int off = 1; off < 64; off <<= 1) {
        const int n = __shfl_up(incl, off);
        if (lane >= off) incl += n;
    }
    if (lane == 63) wtot[wid] = incl;
    __syncthreads();
    if (wid == 0 && lane < 16) {
        const int v = wtot[lane];
        int s2 = v;
        #pragma unroll
        for (int off = 1; off < 16; off <<= 1) {
            const int n = __shfl_up(s2, off);
            if (lane >= off) s2 += n;
        }
        wtot[lane] = s2 - v;    // exclusive wave offsets
    }
    __syncthreads();
    if (t < NB) {
        const int excl = incl - hv + wtot[wid];
        lh[t]   = excl;
        lcur[t] = excl;
        gbase[t] = (hv > 0) ? atomicAdd(&bcursor[t], hv) : 0;
    }
    __syncthreads();

    #pragma unroll
    for (int j = 0; j < PEPT; ++j) {
        if (bkt[j] >= 0) {
            const int lp = atomicAdd(&lcur[bkt[j]], 1);
            stage[lp] = ent[j];
            gpos[lp]  = gbase[bkt[j]] + (lp - lh[bkt[j]]);
        }
    }
    __syncthreads();

    for (int i = t; i < cnt; i += PTHREADS)
        staging[gpos[i]] = stage[i];
}

// ---------------- bucket sort: staging -> node-ordered sdst (verified R6) -----------
__global__ __launch_bounds__(1024) void bucket_sort_kernel(
    const unsigned* __restrict__ staging, const int* __restrict__ offs,
    int* __restrict__ sdst)
{
    __shared__ int ldst[ECAP];           // 24 KB
    __shared__ int lcur[BNODES];
    const int t = threadIdx.x;
    const int b = blockIdx.x;
    const int nbase = b * BNODES;
    const int base0 = offs[nbase];
    const int endoff = (b == NB - 1) ? NE : offs[nbase + BNODES];
    const int ecnt = endoff - base0;
    const int nvalid = min(BNODES, NN - nbase);

    if (t < BNODES) lcur[t] = (t < nvalid) ? (offs[nbase + t] - base0) : 0;
    __syncthreads();
    for (int i = t; i < ecnt; i += 1024) {
        const unsigned ev = staging[base0 + i];
        const int lp = atomicAdd(&lcur[(int)(ev >> 17)], 1);
        ldst[lp] = (int)(ev & 0x1FFFFu);
    }
    __syncthreads();
    for (int i = t; i < ecnt; i += 1024)
        sdst[base0 + i] = ldst[i];
}

// ------ fused gather(mean) + MLP + heads: uniform fp16 rows, 16-deep pipeline ------
__global__ __launch_bounds__(256) void gather_head_kernel(
    const __half* __restrict__ h16,
    const int* __restrict__ counts, const int* __restrict__ offs,
    const int* __restrict__ sdst,
    const float* __restrict__ Wf1, const float* __restrict__ bf1,
    const float* __restrict__ Wf2, const float* __restrict__ bf2,
    const float* __restrict__ Ws1, const float* __restrict__ bs1,
    const float* __restrict__ Ws2, const float* __restrict__ bs2,
    const float* __restrict__ Wt1, const float* __restrict__ bt1,
    const float* __restrict__ Wt2, const float* __restrict__ bt2,
    float* __restrict__ out_scores, float* __restrict__ out_types)
{
    __shared__ float sa[4][H];
    __shared__ float sb[4][H];
    const int tid  = threadIdx.x;
    const int slot = tid >> 6;
    const int f    = tid & 63;
    const int node = blockIdx.x * 4 + slot;   // grid 25000 -> node < NN always

    const int deg   = counts[node];
    const int start = offs[node];

    const float selfv = __half2float(h16[((size_t)node << 6) + f]);  // issued early

    float acc = 0.0f;
    for (int base = 0; base < deg; base += 64) {
        const int m = min(64, deg - base);
        int idx = 0;
        if (base + f < deg) idx = sdst[start + base + f];   // coalesced vector load

        int jj = 0;
        for (; jj + 16 <= m; jj += 16) {                    // 16 uniform rows in flight
            __half hv[16];
            #pragma unroll
            for (int u = 0; u < 16; ++u) {
                const int d = __shfl(idx, jj + u);
                hv[u] = h16[((size_t)d << 6) + f];
            }
            #pragma unroll
            for (int u = 0; u < 16; ++u)
                acc += __half2float(hv[u]);
        }
        if (jj + 8 <= m) {                                  // 8-deep tail
            __half hv[8];
            #pragma unroll
            for (int u = 0; u < 8; ++u) {
                const int d = __shfl(idx, jj + u);
                hv[u] = h16[((size_t)d << 6) + f];
            }
            #pragma unroll
            for (int u = 0; u < 8; ++u)
                acc += __half2float(hv[u]);
            jj += 8;
        }
        for (; jj < m; ++jj) {
            const int d = __shfl(idx, jj);
            acc += __half2float(h16[((size_t)d << 6) + f]);
        }
    }

    const float inv = 1.0f / fmaxf((float)deg, 1.0f);
    sa[slot][f] = selfv + acc * inv;
    __syncthreads();

    {
        float a2 = bf1[f];
        #pragma unroll 8
        for (int k = 0; k < H; ++k)
            a2 = fmaf(sa[slot][k], Wf1[k * H + f], a2);
        sb[slot][f] = fmaxf(a2, 0.0f);
    }
    __syncthreads();

    {
        float a2 = bf2[f];
        #pragma unroll 8
        for (int k = 0; k < H; ++k)
            a2 = fmaf(sb[slot][k], Wf2[k * H + f], a2);
        sa[slot][f] = fmaxf(a2, 0.0f);
    }
    __syncthreads();

    {
        if (f < 32) {
            float a2 = bs1[f];
            #pragma unroll 8
            for (int k = 0; k < H; ++k)
                a2 = fmaf(sa[slot][k], Ws1[k * 32 + f], a2);
            sb[slot][f] = fmaxf(a2, 0.0f);
        } else {
            const int jj = f - 32;
            float a2 = bt1[jj];
            #pragma unroll 8
            for (int k = 0; k < H; ++k)
                a2 = fmaf(sa[slot][k], Wt1[k * 32 + jj], a2);
            sb[slot][32 + jj] = fmaxf(a2, 0.0f);
        }
    }
    __syncthreads();

    {
        if (f == 0) {
            float a2 = bs2[0];
            #pragma unroll 8
            for (int jj = 0; jj < 32; ++jj)
                a2 = fmaf(sb[slot][jj], Ws2[jj], a2);
            out_scores[node] = a2;
        } else if (f >= 1 && f < 5) {
            const int c = f - 1;
            float a2 = bt2[c];
            #pragma unroll 8
            for (int jj = 0; jj < 32; ++jj)
                a2 = fmaf(sb[slot][32 + jj], Wt2[jj * 4 + c], a2);
            out_types[node * 4 + c] = a2;
        }
    }
}

extern "C" void kernel_launch(void* const* d_in, const int* in_sizes, int n_in,
                              void* d_out, int out_size, void* d_ws, size_t ws_size,
                              hipStream_t stream)
{
    const float* x   = (const float*)d_in[0];
    const int*   adj = (const int*)  d_in[1];   // [2, E]: src = adj[0:E], dst = adj[E:2E]
    const float* W1  = (const float*)d_in[2];
    const float* b1  = (const float*)d_in[3];
    const float* W2  = (const float*)d_in[4];
    const float* b2  = (const float*)d_in[5];
    const float* Wf1 = (const float*)d_in[6];
    const float* bf1 = (const float*)d_in[7];
    const float* Wf2 = (const float*)d_in[8];
    const float* bf2 = (const float*)d_in[9];
    const float* Ws1 = (const float*)d_in[10];
    const float* bs1 = (const float*)d_in[11];
    const float* Ws2 = (const float*)d_in[12];
    const float* bs2 = (const float*)d_in[13];
    const float* Wt1 = (const float*)d_in[14];
    const float* bt1 = (const float*)d_in[15];
    const float* Wt2 = (const float*)d_in[16];
    const float* bt2 = (const float*)d_in[17];

    float* out_scores = (float*)d_out;          // [N]
    float* out_types  = out_scores + NN;        // [N,4]

    // ws: staging [NE u32] | h16 [NN*H half] | counts [NN] | offs [NN] | partials [128]
    //     | bcursor [NB] | sdst [NE]
    unsigned* staging  = (unsigned*)d_ws;
    __half*   h16      = (__half*)(staging + NE);
    int*      counts   = (int*)(h16 + (size_t)NN * H);
    int*      offs     = counts + NN;
    int*      partials = offs + NN;
    int*      bcursor  = partials + 128;
    int*      sdst     = bcursor + NB;

    const int* src = adj;
    const int* dst = adj + NE;

    hipMemsetAsync(counts, 0, NN * sizeof(int), stream);

    encoder_count_kernel<<<NN / 4, 256, 0, stream>>>(x, W1, b1, W2, b2, src, counts, h16);
    scan1_kernel<<<NB1, SCAN_BLOCK, 0, stream>>>(counts, offs, partials);
    scan2_kernel<<<1, 128, 0, stream>>>(partials);
    scan3_kernel<<<NB1, SCAN_BLOCK, 0, stream>>>(offs, partials, bcursor);
    partition_kernel<<<NPBLK, PTHREADS, 0, stream>>>(src, dst, bcursor, staging);
    bucket_sort_kernel<<<NB, 1024, 0, stream>>>(staging, offs, sdst);
    gather_head_kernel<<<NN / 4, 256, 0, stream>>>(h16, counts, offs, sdst,
                                                   Wf1, bf1, Wf2, bf2,
                                                   Ws1, bs1, Ws2, bs2,
                                                   Wt1, bt1, Wt2, bt2,
                                                   out_scores, out_types);
}